// Round 1
// baseline (6479.667 us; speedup 1.0000x reference)
//
#include <hip/hip_runtime.h>
#include <hip/hip_bf16.h>

#define NSEQ 512
#define WD   256
#define LD   256
#define NG   1024      // 4*LD gates
#define FEAT 512
#define HID  512
#define NREL 100

__device__ __forceinline__ float fsig(float x) {
    x = fminf(fmaxf(x, -30.f), 30.f);
    return 1.f / (1.f + __expf(-x));
}
__device__ __forceinline__ float ftanh(float x) {
    x = fminf(fmaxf(x, -15.f), 15.f);
    float e = __expf(2.f * x);
    return (e - 1.f) / (e + 1.f);
}

// ---------------- embedding gather ----------------
__global__ void embed_kernel(const int* __restrict__ tok, const float* __restrict__ E,
                             float* __restrict__ x) {
    int b = blockIdx.x;
    int t = tok[b];
    x[b * WD + threadIdx.x] = E[(long long)t * WD + threadIdx.x];
}

// ---------------- generic tiled GEMM: C = A(MxK) @ W(KxN) + bias ----------------
__global__ __launch_bounds__(256) void gemm_bias_kernel(
        const float* __restrict__ A, const float* __restrict__ W,
        const float* __restrict__ bias, float* __restrict__ C,
        int M, int K, int N) {
    __shared__ float As[16][65];
    alignas(16) __shared__ float Ws[16][68];
    int tid = threadIdx.x;
    int m0 = blockIdx.y * 64, n0 = blockIdx.x * 64;
    int tx = tid & 15, ty = tid >> 4;
    float acc[4][4] = {};
    int am = tid >> 2, akq = (tid & 3) * 4;
    int wk = tid >> 4, wn = (tid & 15) * 4;
    for (int k0 = 0; k0 < K; k0 += 16) {
        float4 av = *(const float4*)&A[(m0 + am) * K + k0 + akq];
        As[akq + 0][am] = av.x; As[akq + 1][am] = av.y;
        As[akq + 2][am] = av.z; As[akq + 3][am] = av.w;
        float4 wv = *(const float4*)&W[(k0 + wk) * N + n0 + wn];
        *(float4*)&Ws[wk][wn] = wv;
        __syncthreads();
        #pragma unroll
        for (int kk = 0; kk < 16; ++kk) {
            float a[4], w[4];
            #pragma unroll
            for (int q = 0; q < 4; ++q) { a[q] = As[kk][ty * 4 + q]; w[q] = Ws[kk][tx * 4 + q]; }
            #pragma unroll
            for (int i = 0; i < 4; ++i)
                #pragma unroll
                for (int j = 0; j < 4; ++j) acc[i][j] = fmaf(a[i], w[j], acc[i][j]);
        }
        __syncthreads();
    }
    #pragma unroll
    for (int i = 0; i < 4; ++i) {
        int row = m0 + ty * 4 + i;
        #pragma unroll
        for (int j = 0; j < 4; ++j) {
            int colx = n0 + tx * 4 + j;
            float b = bias ? bias[colx] : 0.f;
            C[row * N + colx] = acc[i][j] + b;
        }
    }
}

// ---------------- bidirectional LSTM layer ----------------
// Grid: 8 blocks x 1024 threads. blocks 0-3: forward, 4-7: backward.
// Each block owns 64 h-outputs (256 gates); Wh slice register-resident
// (64 f32/thread). Per-step h exchange through global (L2) + flag counter.
__global__ __launch_bounds__(1024) void lstm_kernel(
        const float* __restrict__ Xf, const float* __restrict__ Xb,
        const float* __restrict__ WhF, const float* __restrict__ WhB,
        float* __restrict__ H, int* __restrict__ flags) {
    int tid = threadIdx.x;
    int dir = blockIdx.x >> 2;
    int blk = blockIdx.x & 3;
    const float* X  = dir ? Xb : Xf;
    const float* Wh = dir ? WhB : WhF;
    int* flg = flags + dir * NSEQ;
    int gl = tid & 255;            // local gate index: type*64 + jj
    int ks = tid >> 8;             // k-slice 0..3 (64 k each)
    int jj = gl & 63, gt = gl >> 6;
    int col = gt * 256 + blk * 64 + jj;   // global gate column in [0,1024)
    float w[64];
    #pragma unroll
    for (int m = 0; m < 64; ++m) w[m] = Wh[(ks * 64 + m) * NG + col];

    alignas(16) __shared__ float hprev[256];
    __shared__ float partial[4][257];
    __shared__ float zbuf[256];
    if (tid < 256) hprev[tid] = 0.f;
    float c_reg = 0.f;
    __syncthreads();

    for (int s = 0; s < NSEQ; ++s) {
        int t = dir ? (NSEQ - 1 - s) : s;
        float xg = X[t * NG + col];
        float p = 0.f;
        #pragma unroll
        for (int m4 = 0; m4 < 16; ++m4) {
            float4 hv = *(const float4*)&hprev[ks * 64 + m4 * 4];
            p = fmaf(w[m4 * 4 + 0], hv.x, p);
            p = fmaf(w[m4 * 4 + 1], hv.y, p);
            p = fmaf(w[m4 * 4 + 2], hv.z, p);
            p = fmaf(w[m4 * 4 + 3], hv.w, p);
        }
        partial[ks][gl] = p;
        __syncthreads();
        if (tid < 256) {
            zbuf[tid] = xg + partial[0][tid] + partial[1][tid]
                           + partial[2][tid] + partial[3][tid];
        }
        __syncthreads();
        if (tid < 64) {
            float zi = zbuf[tid], zf = zbuf[64 + tid], zg = zbuf[128 + tid], zo = zbuf[192 + tid];
            c_reg = fsig(zf) * c_reg + fsig(zi) * ftanh(zg);
            float h = fsig(zo) * ftanh(c_reg);
            H[t * FEAT + dir * LD + blk * 64 + tid] = h;
        }
        __threadfence();
        __syncthreads();
        if (tid == 0)
            __hip_atomic_fetch_add(&flg[s], 1, __ATOMIC_RELEASE, __HIP_MEMORY_SCOPE_AGENT);
        if (s + 1 < NSEQ) {
            if (tid == 0) {
                while (__hip_atomic_load(&flg[s], __ATOMIC_ACQUIRE, __HIP_MEMORY_SCOPE_AGENT) < 4)
                    __builtin_amdgcn_s_sleep(1);
            }
            __syncthreads();
            if (tid < 256) hprev[tid] = H[t * FEAT + dir * LD + tid];
            __syncthreads();
        }
    }
}

// ---------------- arc scorer: out[i,j] = tanh(Hh[i]+Mh[j]) . outW + outB ----------------
// (hidBias folded into Hh by the GEMM)
__global__ __launch_bounds__(256) void arc_kernel(
        const float* __restrict__ Hh, const float* __restrict__ Mh,
        const float* __restrict__ outW, const float* __restrict__ outB,
        float* __restrict__ out) {
    __shared__ float Hs[16][513];
    __shared__ float Ms[16][513];
    __shared__ float wW[512];
    int tid = threadIdx.x;
    int i0 = blockIdx.y * 16, j0 = blockIdx.x * 16;
    int r = tid >> 4, kb = (tid & 15) * 4;
    #pragma unroll
    for (int q = 0; q < 8; ++q) {
        int k = kb + q * 64;
        float4 hv = *(const float4*)&Hh[(i0 + r) * HID + k];
        Hs[r][k] = hv.x; Hs[r][k + 1] = hv.y; Hs[r][k + 2] = hv.z; Hs[r][k + 3] = hv.w;
        float4 mv = *(const float4*)&Mh[(j0 + r) * HID + k];
        Ms[r][k] = mv.x; Ms[r][k + 1] = mv.y; Ms[r][k + 2] = mv.z; Ms[r][k + 3] = mv.w;
    }
    wW[tid] = outW[tid];
    wW[tid + 256] = outW[tid + 256];
    __syncthreads();
    int ti = tid >> 4, tj = tid & 15;
    float acc = 0.f;
    #pragma unroll 4
    for (int k = 0; k < 512; ++k)
        acc += ftanh(Hs[ti][k] + Ms[tj][k]) * wW[k];
    out[(i0 + ti) * NSEQ + (j0 + tj)] = acc + outB[0];
}

// ---------------- relation scorer ----------------
// block: one head i, 64 mods j. K split in 8 chunks of 64.
// per chunk: stage routW chunk + Rh chunk in LDS, compute act (tanh) into LDS,
// then register-tiled 8x4 GEMM. (rhidBias folded into Rh by the GEMM.)
__global__ __launch_bounds__(256) void rel_kernel(
        const float* __restrict__ Rh, const float* __restrict__ Rm,
        const float* __restrict__ routW, const float* __restrict__ routB,
        float* __restrict__ out) {
    alignas(16) __shared__ float act_t[64][68];
    alignas(16) __shared__ float rw[64 * 100];
    __shared__ float rh_s[64];
    int tid = threadIdx.x;
    int i = blockIdx.x >> 3;
    int j0 = (blockIdx.x & 7) * 64;
    int rt = tid % 25, pg = tid / 25;   // valid when tid<200
    bool active = tid < 200;
    float acc[8][4] = {};
    int p = tid & 63, ksl = tid >> 6;
    for (int c = 0; c < 8; ++c) {
        int k0 = c * 64;
        #pragma unroll
        for (int q = 0; q < 25; ++q)
            rw[q * 256 + tid] = routW[k0 * 100 + q * 256 + tid];
        if (tid < 64) rh_s[tid] = Rh[i * HID + k0 + tid];
        __syncthreads();
        #pragma unroll
        for (int kk4 = 0; kk4 < 4; ++kk4) {
            int k = ksl * 16 + kk4 * 4;
            float4 mv = *(const float4*)&Rm[(j0 + p) * HID + k0 + k];
            act_t[k + 0][p] = ftanh(rh_s[k + 0] + mv.x);
            act_t[k + 1][p] = ftanh(rh_s[k + 1] + mv.y);
            act_t[k + 2][p] = ftanh(rh_s[k + 2] + mv.z);
            act_t[k + 3][p] = ftanh(rh_s[k + 3] + mv.w);
        }
        __syncthreads();
        if (active) {
            #pragma unroll 4
            for (int k = 0; k < 64; ++k) {
                float4 a0 = *(const float4*)&act_t[k][pg * 8];
                float4 a1 = *(const float4*)&act_t[k][pg * 8 + 4];
                float4 wv = *(const float4*)&rw[k * 100 + rt * 4];
                float av[8] = {a0.x, a0.y, a0.z, a0.w, a1.x, a1.y, a1.z, a1.w};
                float wf[4] = {wv.x, wv.y, wv.z, wv.w};
                #pragma unroll
                for (int pp = 0; pp < 8; ++pp)
                    #pragma unroll
                    for (int rr = 0; rr < 4; ++rr)
                        acc[pp][rr] = fmaf(av[pp], wf[rr], acc[pp][rr]);
            }
        }
        __syncthreads();
    }
    if (active) {
        #pragma unroll
        for (int pp = 0; pp < 8; ++pp) {
            int j = j0 + pg * 8 + pp;
            #pragma unroll
            for (int rr = 0; rr < 4; ++rr) {
                int rg = rt * 4 + rr;
                out[(long long)(i * NSEQ + j) * NREL + rg] = acc[pp][rr] + routB[rg];
            }
        }
    }
}

extern "C" void kernel_launch(void* const* d_in, const int* in_sizes, int n_in,
                              void* d_out, int out_size, void* d_ws, size_t ws_size,
                              hipStream_t stream) {
    const int*   tokens = (const int*)d_in[0];
    const float* E      = (const float*)d_in[1];
    const float* Wx_f1  = (const float*)d_in[2];
    const float* Wh_f1  = (const float*)d_in[3];
    const float* b_f1   = (const float*)d_in[4];
    const float* Wx_b1  = (const float*)d_in[5];
    const float* Wh_b1  = (const float*)d_in[6];
    const float* b_b1   = (const float*)d_in[7];
    const float* Wx_f2  = (const float*)d_in[8];
    const float* Wh_f2  = (const float*)d_in[9];
    const float* b_f2   = (const float*)d_in[10];
    const float* Wx_b2  = (const float*)d_in[11];
    const float* Wh_b2  = (const float*)d_in[12];
    const float* b_b2   = (const float*)d_in[13];
    const float* hidFOH = (const float*)d_in[14];
    const float* hidFOM = (const float*)d_in[15];
    const float* hidBias= (const float*)d_in[16];
    const float* outW   = (const float*)d_in[17];
    const float* outB   = (const float*)d_in[18];
    const float* rhidFOH= (const float*)d_in[19];
    const float* rhidFOM= (const float*)d_in[20];
    const float* rhidBias=(const float*)d_in[21];
    const float* routW  = (const float*)d_in[22];
    const float* routB  = (const float*)d_in[23];

    float* ws  = (float*)d_ws;
    float* x   = ws;                  // 512*256
    float* Xf1 = x + 131072;          // 512*1024
    float* Xb1 = Xf1 + 524288;
    float* h1  = Xb1 + 524288;        // 512*512
    float* Xf2 = h1 + 262144;
    float* Xb2 = Xf2 + 524288;
    float* h2  = Xb2 + 524288;        // 512*512
    float* Hh  = h2 + 262144;
    float* Mh  = Hh + 262144;
    float* Rh  = Mh + 262144;
    float* Rm  = Rh + 262144;
    int* flags = (int*)(Rm + 262144); // 2048 ints (2 layers x 2 dirs x 512)

    float* arc_out = (float*)d_out;
    float* rel_out = arc_out + NSEQ * NSEQ;

    hipMemsetAsync(flags, 0, 2048 * sizeof(int), stream);
    embed_kernel<<<NSEQ, WD, 0, stream>>>(tokens, E, x);
    dim3 g1(NG / 64, NSEQ / 64);
    gemm_bias_kernel<<<g1, 256, 0, stream>>>(x, Wx_f1, b_f1, Xf1, NSEQ, WD, NG);
    gemm_bias_kernel<<<g1, 256, 0, stream>>>(x, Wx_b1, b_b1, Xb1, NSEQ, WD, NG);
    lstm_kernel<<<8, 1024, 0, stream>>>(Xf1, Xb1, Wh_f1, Wh_b1, h1, flags);
    gemm_bias_kernel<<<g1, 256, 0, stream>>>(h1, Wx_f2, b_f2, Xf2, NSEQ, FEAT, NG);
    gemm_bias_kernel<<<g1, 256, 0, stream>>>(h1, Wx_b2, b_b2, Xb2, NSEQ, FEAT, NG);
    lstm_kernel<<<8, 1024, 0, stream>>>(Xf2, Xb2, Wh_f2, Wh_b2, h2, flags + 1024);
    dim3 g2(HID / 64, NSEQ / 64);
    gemm_bias_kernel<<<g2, 256, 0, stream>>>(h2, hidFOH, hidBias, Hh, NSEQ, FEAT, HID);
    gemm_bias_kernel<<<g2, 256, 0, stream>>>(h2, hidFOM, nullptr, Mh, NSEQ, FEAT, HID);
    gemm_bias_kernel<<<g2, 256, 0, stream>>>(h2, rhidFOH, rhidBias, Rh, NSEQ, FEAT, HID);
    gemm_bias_kernel<<<g2, 256, 0, stream>>>(h2, rhidFOM, nullptr, Rm, NSEQ, FEAT, HID);
    dim3 ga(NSEQ / 16, NSEQ / 16);
    arc_kernel<<<ga, 256, 0, stream>>>(Hh, Mh, outW, outB, arc_out);
    rel_kernel<<<NSEQ * 8, 256, 0, stream>>>(Rh, Rm, routW, routB, rel_out);
}

// Round 2
// 3453.660 us; speedup vs baseline: 1.8762x; 1.8762x over previous
//
#include <hip/hip_runtime.h>
#include <hip/hip_bf16.h>

#define NSEQ 512
#define WD   256
#define LD   256
#define NG   1024      // 4*LD gates
#define FEAT 512
#define HID  512
#define NREL 100

__device__ __forceinline__ float fsig(float x) {
    x = fminf(fmaxf(x, -30.f), 30.f);
    return 1.f / (1.f + __expf(-x));
}
__device__ __forceinline__ float ftanh(float x) {
    x = fminf(fmaxf(x, -15.f), 15.f);
    float e = __expf(2.f * x);
    return (e - 1.f) / (e + 1.f);
}

// Agent-scope relaxed accesses: compile to global_load/store ... sc0 sc1
// (bypass L1+L2, served by Infinity Cache -> coherent across XCDs) with NO
// cache-maintenance instructions (no buffer_inv / buffer_wbl2).
__device__ __forceinline__ void st_agent_f32(float* p, float v) {
    __hip_atomic_store(p, v, __ATOMIC_RELAXED, __HIP_MEMORY_SCOPE_AGENT);
}
__device__ __forceinline__ float ld_agent_f32(const float* p) {
    return __hip_atomic_load((float*)p, __ATOMIC_RELAXED, __HIP_MEMORY_SCOPE_AGENT);
}
__device__ __forceinline__ void st_agent_i32(int* p, int v) {
    __hip_atomic_store(p, v, __ATOMIC_RELAXED, __HIP_MEMORY_SCOPE_AGENT);
}
__device__ __forceinline__ int ld_agent_i32(const int* p) {
    return __hip_atomic_load((int*)p, __ATOMIC_RELAXED, __HIP_MEMORY_SCOPE_AGENT);
}

// ---------------- embedding gather ----------------
__global__ void embed_kernel(const int* __restrict__ tok, const float* __restrict__ E,
                             float* __restrict__ x) {
    int b = blockIdx.x;
    int t = tok[b];
    x[b * WD + threadIdx.x] = E[(long long)t * WD + threadIdx.x];
}

// ---------------- generic tiled GEMM: C = A(MxK) @ W(KxN) + bias ----------------
__global__ __launch_bounds__(256) void gemm_bias_kernel(
        const float* __restrict__ A, const float* __restrict__ W,
        const float* __restrict__ bias, float* __restrict__ C,
        int M, int K, int N) {
    __shared__ float As[16][65];
    alignas(16) __shared__ float Ws[16][68];
    int tid = threadIdx.x;
    int m0 = blockIdx.y * 64, n0 = blockIdx.x * 64;
    int tx = tid & 15, ty = tid >> 4;
    float acc[4][4] = {};
    int am = tid >> 2, akq = (tid & 3) * 4;
    int wk = tid >> 4, wn = (tid & 15) * 4;
    for (int k0 = 0; k0 < K; k0 += 16) {
        float4 av = *(const float4*)&A[(m0 + am) * K + k0 + akq];
        As[akq + 0][am] = av.x; As[akq + 1][am] = av.y;
        As[akq + 2][am] = av.z; As[akq + 3][am] = av.w;
        float4 wv = *(const float4*)&W[(k0 + wk) * N + n0 + wn];
        *(float4*)&Ws[wk][wn] = wv;
        __syncthreads();
        #pragma unroll
        for (int kk = 0; kk < 16; ++kk) {
            float a[4], w[4];
            #pragma unroll
            for (int q = 0; q < 4; ++q) { a[q] = As[kk][ty * 4 + q]; w[q] = Ws[kk][tx * 4 + q]; }
            #pragma unroll
            for (int i = 0; i < 4; ++i)
                #pragma unroll
                for (int j = 0; j < 4; ++j) acc[i][j] = fmaf(a[i], w[j], acc[i][j]);
        }
        __syncthreads();
    }
    #pragma unroll
    for (int i = 0; i < 4; ++i) {
        int row = m0 + ty * 4 + i;
        #pragma unroll
        for (int j = 0; j < 4; ++j) {
            int colx = n0 + tx * 4 + j;
            float b = bias ? bias[colx] : 0.f;
            C[row * N + colx] = acc[i][j] + b;
        }
    }
}

// ---------------- bidirectional LSTM layer ----------------
// Grid: 8 blocks x 1024 threads. blocks 0-3: forward, 4-7: backward.
// Each block owns 64 h-outputs (256 gates); Wh slice register-resident
// (64 f32/thread). Per-step exchange via IC (sc0 sc1) relaxed atomics +
// monotonic per-block step flags. NO fences / RMW atomics in the loop.
__global__ __launch_bounds__(1024) void lstm_kernel(
        const float* __restrict__ Xf, const float* __restrict__ Xb,
        const float* __restrict__ WhF, const float* __restrict__ WhB,
        float* __restrict__ H, int* __restrict__ flags) {
    int tid = threadIdx.x;
    int dir = blockIdx.x >> 2;
    int blk = blockIdx.x & 3;
    const float* X  = dir ? Xb : Xf;
    const float* Wh = dir ? WhB : WhF;
    int* flg = flags + dir * 4;    // 4 monotonic step counters per direction
    int gl = tid & 255;            // local gate index: type*64 + jj
    int ks = tid >> 8;             // k-slice 0..3 (64 k each)
    int jj = gl & 63, gt = gl >> 6;
    int col = gt * 256 + blk * 64 + jj;   // global gate column in [0,1024)
    float w[64];
    #pragma unroll
    for (int m = 0; m < 64; ++m) w[m] = Wh[(ks * 64 + m) * NG + col];

    alignas(16) __shared__ float hprev[256];
    __shared__ float partial[4][257];
    __shared__ float zbuf[256];
    if (tid < 256) hprev[tid] = 0.f;
    float c_reg = 0.f;
    __syncthreads();

    for (int s = 0; s < NSEQ; ++s) {
        int t = dir ? (NSEQ - 1 - s) : s;
        float xg = X[t * NG + col];
        // k-sliced dot product, 4-way accumulator split to break the dep chain
        float pa[4] = {0.f, 0.f, 0.f, 0.f};
        #pragma unroll
        for (int q = 0; q < 16; ++q) {
            float4 hv = *(const float4*)&hprev[ks * 64 + q * 4];
            pa[q & 3] = fmaf(w[q * 4 + 0], hv.x, pa[q & 3]);
            pa[q & 3] = fmaf(w[q * 4 + 1], hv.y, pa[q & 3]);
            pa[q & 3] = fmaf(w[q * 4 + 2], hv.z, pa[q & 3]);
            pa[q & 3] = fmaf(w[q * 4 + 3], hv.w, pa[q & 3]);
        }
        partial[ks][gl] = (pa[0] + pa[1]) + (pa[2] + pa[3]);
        __syncthreads();
        if (tid < 256) {
            zbuf[tid] = xg + partial[0][tid] + partial[1][tid]
                           + partial[2][tid] + partial[3][tid];
        }
        __syncthreads();
        if (tid < 64) {
            float zi = zbuf[tid], zf = zbuf[64 + tid], zg = zbuf[128 + tid], zo = zbuf[192 + tid];
            c_reg = fsig(zf) * c_reg + fsig(zi) * ftanh(zg);
            float h = fsig(zo) * ftanh(c_reg);
            st_agent_f32(&H[t * FEAT + dir * LD + blk * 64 + tid], h);   // to IC
        }
        // order data stores (wave 0) before the flag store (tid 0, same wave)
        asm volatile("s_waitcnt vmcnt(0)" ::: "memory");
        if (tid == 0) st_agent_i32(&flg[blk], s + 1);
        if (s + 1 < NSEQ) {
            if (tid < 4) {
                while (ld_agent_i32(&flg[tid]) <= s) { /* spin on IC */ }
            }
            __syncthreads();
            asm volatile("" ::: "memory");
            if (tid < 256) hprev[tid] = ld_agent_f32(&H[t * FEAT + dir * LD + tid]);
            __syncthreads();
        }
    }
}

// ---------------- arc scorer: out[i,j] = tanh(Hh[i]+Mh[j]) . outW + outB ----------------
// (hidBias folded into Hh by the GEMM)
__global__ __launch_bounds__(256) void arc_kernel(
        const float* __restrict__ Hh, const float* __restrict__ Mh,
        const float* __restrict__ outW, const float* __restrict__ outB,
        float* __restrict__ out) {
    __shared__ float Hs[16][513];
    __shared__ float Ms[16][513];
    __shared__ float wW[512];
    int tid = threadIdx.x;
    int i0 = blockIdx.y * 16, j0 = blockIdx.x * 16;
    int r = tid >> 4, kb = (tid & 15) * 4;
    #pragma unroll
    for (int q = 0; q < 8; ++q) {
        int k = kb + q * 64;
        float4 hv = *(const float4*)&Hh[(i0 + r) * HID + k];
        Hs[r][k] = hv.x; Hs[r][k + 1] = hv.y; Hs[r][k + 2] = hv.z; Hs[r][k + 3] = hv.w;
        float4 mv = *(const float4*)&Mh[(j0 + r) * HID + k];
        Ms[r][k] = mv.x; Ms[r][k + 1] = mv.y; Ms[r][k + 2] = mv.z; Ms[r][k + 3] = mv.w;
    }
    wW[tid] = outW[tid];
    wW[tid + 256] = outW[tid + 256];
    __syncthreads();
    int ti = tid >> 4, tj = tid & 15;
    float acc = 0.f;
    #pragma unroll 4
    for (int k = 0; k < 512; ++k)
        acc += ftanh(Hs[ti][k] + Ms[tj][k]) * wW[k];
    out[(i0 + ti) * NSEQ + (j0 + tj)] = acc + outB[0];
}

// ---------------- relation scorer ----------------
// block: one head i, 64 mods j. K split in 8 chunks of 64.
// per chunk: stage routW chunk + Rh chunk in LDS, compute act (tanh) into LDS,
// then register-tiled 8x4 GEMM. (rhidBias folded into Rh by the GEMM.)
__global__ __launch_bounds__(256) void rel_kernel(
        const float* __restrict__ Rh, const float* __restrict__ Rm,
        const float* __restrict__ routW, const float* __restrict__ routB,
        float* __restrict__ out) {
    alignas(16) __shared__ float act_t[64][68];
    alignas(16) __shared__ float rw[64 * 100];
    __shared__ float rh_s[64];
    int tid = threadIdx.x;
    int i = blockIdx.x >> 3;
    int j0 = (blockIdx.x & 7) * 64;
    int rt = tid % 25, pg = tid / 25;   // valid when tid<200
    bool active = tid < 200;
    float acc[8][4] = {};
    int p = tid & 63, ksl = tid >> 6;
    for (int c = 0; c < 8; ++c) {
        int k0 = c * 64;
        #pragma unroll
        for (int q = 0; q < 25; ++q)
            rw[q * 256 + tid] = routW[k0 * 100 + q * 256 + tid];
        if (tid < 64) rh_s[tid] = Rh[i * HID + k0 + tid];
        __syncthreads();
        #pragma unroll
        for (int kk4 = 0; kk4 < 4; ++kk4) {
            int k = ksl * 16 + kk4 * 4;
            float4 mv = *(const float4*)&Rm[(j0 + p) * HID + k0 + k];
            act_t[k + 0][p] = ftanh(rh_s[k + 0] + mv.x);
            act_t[k + 1][p] = ftanh(rh_s[k + 1] + mv.y);
            act_t[k + 2][p] = ftanh(rh_s[k + 2] + mv.z);
            act_t[k + 3][p] = ftanh(rh_s[k + 3] + mv.w);
        }
        __syncthreads();
        if (active) {
            #pragma unroll 4
            for (int k = 0; k < 64; ++k) {
                float4 a0 = *(const float4*)&act_t[k][pg * 8];
                float4 a1 = *(const float4*)&act_t[k][pg * 8 + 4];
                float4 wv = *(const float4*)&rw[k * 100 + rt * 4];
                float av[8] = {a0.x, a0.y, a0.z, a0.w, a1.x, a1.y, a1.z, a1.w};
                float wf[4] = {wv.x, wv.y, wv.z, wv.w};
                #pragma unroll
                for (int pp = 0; pp < 8; ++pp)
                    #pragma unroll
                    for (int rr = 0; rr < 4; ++rr)
                        acc[pp][rr] = fmaf(av[pp], wf[rr], acc[pp][rr]);
            }
        }
        __syncthreads();
    }
    if (active) {
        #pragma unroll
        for (int pp = 0; pp < 8; ++pp) {
            int j = j0 + pg * 8 + pp;
            #pragma unroll
            for (int rr = 0; rr < 4; ++rr) {
                int rg = rt * 4 + rr;
                out[(long long)(i * NSEQ + j) * NREL + rg] = acc[pp][rr] + routB[rg];
            }
        }
    }
}

extern "C" void kernel_launch(void* const* d_in, const int* in_sizes, int n_in,
                              void* d_out, int out_size, void* d_ws, size_t ws_size,
                              hipStream_t stream) {
    const int*   tokens = (const int*)d_in[0];
    const float* E      = (const float*)d_in[1];
    const float* Wx_f1  = (const float*)d_in[2];
    const float* Wh_f1  = (const float*)d_in[3];
    const float* b_f1   = (const float*)d_in[4];
    const float* Wx_b1  = (const float*)d_in[5];
    const float* Wh_b1  = (const float*)d_in[6];
    const float* b_b1   = (const float*)d_in[7];
    const float* Wx_f2  = (const float*)d_in[8];
    const float* Wh_f2  = (const float*)d_in[9];
    const float* b_f2   = (const float*)d_in[10];
    const float* Wx_b2  = (const float*)d_in[11];
    const float* Wh_b2  = (const float*)d_in[12];
    const float* b_b2   = (const float*)d_in[13];
    const float* hidFOH = (const float*)d_in[14];
    const float* hidFOM = (const float*)d_in[15];
    const float* hidBias= (const float*)d_in[16];
    const float* outW   = (const float*)d_in[17];
    const float* outB   = (const float*)d_in[18];
    const float* rhidFOH= (const float*)d_in[19];
    const float* rhidFOM= (const float*)d_in[20];
    const float* rhidBias=(const float*)d_in[21];
    const float* routW  = (const float*)d_in[22];
    const float* routB  = (const float*)d_in[23];

    float* ws  = (float*)d_ws;
    float* x   = ws;                  // 512*256
    float* Xf1 = x + 131072;          // 512*1024
    float* Xb1 = Xf1 + 524288;
    float* h1  = Xb1 + 524288;        // 512*512
    float* Xf2 = h1 + 262144;
    float* Xb2 = Xf2 + 524288;
    float* h2  = Xb2 + 524288;        // 512*512
    float* Hh  = h2 + 262144;
    float* Mh  = Hh + 262144;
    float* Rh  = Mh + 262144;
    float* Rm  = Rh + 262144;
    int* flags = (int*)(Rm + 262144); // 2048 ints (2 layers worth of regions)

    float* arc_out = (float*)d_out;
    float* rel_out = arc_out + NSEQ * NSEQ;

    hipMemsetAsync(flags, 0, 2048 * sizeof(int), stream);
    embed_kernel<<<NSEQ, WD, 0, stream>>>(tokens, E, x);
    dim3 g1(NG / 64, NSEQ / 64);
    gemm_bias_kernel<<<g1, 256, 0, stream>>>(x, Wx_f1, b_f1, Xf1, NSEQ, WD, NG);
    gemm_bias_kernel<<<g1, 256, 0, stream>>>(x, Wx_b1, b_b1, Xb1, NSEQ, WD, NG);
    lstm_kernel<<<8, 1024, 0, stream>>>(Xf1, Xb1, Wh_f1, Wh_b1, h1, flags);
    gemm_bias_kernel<<<g1, 256, 0, stream>>>(h1, Wx_f2, b_f2, Xf2, NSEQ, FEAT, NG);
    gemm_bias_kernel<<<g1, 256, 0, stream>>>(h1, Wx_b2, b_b2, Xb2, NSEQ, FEAT, NG);
    lstm_kernel<<<8, 1024, 0, stream>>>(Xf2, Xb2, Wh_f2, Wh_b2, h2, flags + 1024);
    dim3 g2(HID / 64, NSEQ / 64);
    gemm_bias_kernel<<<g2, 256, 0, stream>>>(h2, hidFOH, hidBias, Hh, NSEQ, FEAT, HID);
    gemm_bias_kernel<<<g2, 256, 0, stream>>>(h2, hidFOM, nullptr, Mh, NSEQ, FEAT, HID);
    gemm_bias_kernel<<<g2, 256, 0, stream>>>(h2, rhidFOH, rhidBias, Rh, NSEQ, FEAT, HID);
    gemm_bias_kernel<<<g2, 256, 0, stream>>>(h2, rhidFOM, nullptr, Rm, NSEQ, FEAT, HID);
    dim3 ga(NSEQ / 16, NSEQ / 16);
    arc_kernel<<<ga, 256, 0, stream>>>(Hh, Mh, outW, outB, arc_out);
    rel_kernel<<<NSEQ * 8, 256, 0, stream>>>(Rh, Rm, routW, routB, rel_out);
}

// Round 3
// 2781.672 us; speedup vs baseline: 2.3294x; 1.2416x over previous
//
#include <hip/hip_runtime.h>
#include <hip/hip_bf16.h>

#define NSEQ 512
#define WD   256
#define LD   256
#define NG   1024      // 4*LD gates
#define FEAT 512
#define HID  512
#define NREL 100

__device__ __forceinline__ float fsig(float x) {
    x = fminf(fmaxf(x, -30.f), 30.f);
    return 1.f / (1.f + __expf(-x));
}
__device__ __forceinline__ float ftanh(float x) {
    x = fminf(fmaxf(x, -15.f), 15.f);
    float e = __expf(2.f * x);
    return (e - 1.f) / (e + 1.f);
}

// ---------------- embedding gather ----------------
__global__ void embed_kernel(const int* __restrict__ tok, const float* __restrict__ E,
                             float* __restrict__ x) {
    int b = blockIdx.x;
    int t = tok[b];
    x[b * WD + threadIdx.x] = E[(long long)t * WD + threadIdx.x];
}

// ---------------- generic tiled GEMM: C = A(MxK) @ W(KxN) + bias ----------------
__global__ __launch_bounds__(256) void gemm_bias_kernel(
        const float* __restrict__ A, const float* __restrict__ W,
        const float* __restrict__ bias, float* __restrict__ C,
        int M, int K, int N) {
    __shared__ float As[16][65];
    alignas(16) __shared__ float Ws[16][68];
    int tid = threadIdx.x;
    int m0 = blockIdx.y * 64, n0 = blockIdx.x * 64;
    int tx = tid & 15, ty = tid >> 4;
    float acc[4][4] = {};
    int am = tid >> 2, akq = (tid & 3) * 4;
    int wk = tid >> 4, wn = (tid & 15) * 4;
    for (int k0 = 0; k0 < K; k0 += 16) {
        float4 av = *(const float4*)&A[(m0 + am) * K + k0 + akq];
        As[akq + 0][am] = av.x; As[akq + 1][am] = av.y;
        As[akq + 2][am] = av.z; As[akq + 3][am] = av.w;
        float4 wv = *(const float4*)&W[(k0 + wk) * N + n0 + wn];
        *(float4*)&Ws[wk][wn] = wv;
        __syncthreads();
        #pragma unroll
        for (int kk = 0; kk < 16; ++kk) {
            float a[4], w[4];
            #pragma unroll
            for (int q = 0; q < 4; ++q) { a[q] = As[kk][ty * 4 + q]; w[q] = Ws[kk][tx * 4 + q]; }
            #pragma unroll
            for (int i = 0; i < 4; ++i)
                #pragma unroll
                for (int j = 0; j < 4; ++j) acc[i][j] = fmaf(a[i], w[j], acc[i][j]);
        }
        __syncthreads();
    }
    #pragma unroll
    for (int i = 0; i < 4; ++i) {
        int row = m0 + ty * 4 + i;
        #pragma unroll
        for (int j = 0; j < 4; ++j) {
            int colx = n0 + tx * 4 + j;
            float b = bias ? bias[colx] : 0.f;
            C[row * N + colx] = acc[i][j] + b;
        }
    }
}

// ---------------- bidirectional LSTM layer ----------------
// Grid: 8 blocks x 1024 threads. blocks 0-3: forward, 4-7: backward.
// Each block owns 64 h-outputs (256 gates); Wh slice register-resident.
// Cross-block exchange: packed (tag,value) u64 per h element, stored once to
// IC (relaxed agent atomics -> sc0 sc1, no cache maintenance). Readers poll
// the data word directly -> ONE IC round-trip per step. Double-buffered by
// step parity; producer's own chunk short-circuits through LDS.
__global__ __launch_bounds__(1024) void lstm_kernel(
        const float* __restrict__ Xf, const float* __restrict__ Xb,
        const float* __restrict__ WhF, const float* __restrict__ WhB,
        float* __restrict__ H, unsigned long long* __restrict__ stage) {
    int tid = threadIdx.x;
    int dir = blockIdx.x >> 2;
    int blk = blockIdx.x & 3;
    const float* X  = dir ? Xb : Xf;
    const float* Wh = dir ? WhB : WhF;
    unsigned long long* stg = stage + dir * 512;   // [2 slots][256] u64
    int gl = tid & 255;            // local gate index: type*64 + jj
    int ks = tid >> 8;             // k-slice 0..3 (64 k each)
    int jj = gl & 63, gt = gl >> 6;
    int col = gt * 256 + blk * 64 + jj;   // global gate column in [0,1024)
    float w[64];
    #pragma unroll
    for (int m = 0; m < 64; ++m) w[m] = Wh[(ks * 64 + m) * NG + col];

    alignas(16) __shared__ float hprev[256];
    __shared__ float partial[4][257];
    if (tid < 256) hprev[tid] = 0.f;
    float c_reg = 0.f;
    int chunk = tid >> 6;          // which 64-chunk this thread polls (tid<256)
    __syncthreads();

    for (int s = 0; s < NSEQ; ++s) {
        int t = dir ? (NSEQ - 1 - s) : s;
        // prefetch x-gates for the activation wave (in flight during the poll)
        float xg4[4];
        if (tid < 64) {
            #pragma unroll
            for (int g = 0; g < 4; ++g)
                xg4[g] = X[t * NG + g * 256 + blk * 64 + tid];
        }
        if (s) {
            if (tid < 256 && chunk != blk) {
                unsigned long long* src = &stg[((s - 1) & 1) * 256 + tid];
                unsigned long long pk;
                do {
                    pk = __hip_atomic_load(src, __ATOMIC_RELAXED, __HIP_MEMORY_SCOPE_AGENT);
                } while ((unsigned)(pk >> 32) != (unsigned)s);
                hprev[tid] = __uint_as_float((unsigned)(pk & 0xffffffffu));
            }
            __syncthreads();
        }
        // k-sliced dot product, 4-way accumulator split
        float pa[4] = {0.f, 0.f, 0.f, 0.f};
        #pragma unroll
        for (int q = 0; q < 16; ++q) {
            float4 hv = *(const float4*)&hprev[ks * 64 + q * 4];
            pa[q & 3] = fmaf(w[q * 4 + 0], hv.x, pa[q & 3]);
            pa[q & 3] = fmaf(w[q * 4 + 1], hv.y, pa[q & 3]);
            pa[q & 3] = fmaf(w[q * 4 + 2], hv.z, pa[q & 3]);
            pa[q & 3] = fmaf(w[q * 4 + 3], hv.w, pa[q & 3]);
        }
        partial[ks][gl] = (pa[0] + pa[1]) + (pa[2] + pa[3]);
        __syncthreads();
        if (tid < 64) {
            float z[4];
            #pragma unroll
            for (int g = 0; g < 4; ++g)
                z[g] = xg4[g] + partial[0][g * 64 + tid] + partial[1][g * 64 + tid]
                              + partial[2][g * 64 + tid] + partial[3][g * 64 + tid];
            c_reg = fsig(z[1]) * c_reg + fsig(z[0]) * ftanh(z[2]);
            float h = fsig(z[3]) * ftanh(c_reg);
            H[t * FEAT + dir * LD + blk * 64 + tid] = h;   // kernel output (plain)
            hprev[blk * 64 + tid] = h;                     // own chunk via LDS
            unsigned long long pk = ((unsigned long long)(unsigned)(s + 1) << 32)
                                  | (unsigned long long)__float_as_uint(h);
            __hip_atomic_store(&stg[(s & 1) * 256 + blk * 64 + tid], pk,
                               __ATOMIC_RELAXED, __HIP_MEMORY_SCOPE_AGENT);
        }
    }
}

// ---------------- arc scorer: out[i,j] = tanh(Hh[i]+Mh[j]) . outW + outB ----------------
// (hidBias folded into Hh by the GEMM)
__global__ __launch_bounds__(256) void arc_kernel(
        const float* __restrict__ Hh, const float* __restrict__ Mh,
        const float* __restrict__ outW, const float* __restrict__ outB,
        float* __restrict__ out) {
    __shared__ float Hs[16][513];
    __shared__ float Ms[16][513];
    __shared__ float wW[512];
    int tid = threadIdx.x;
    int i0 = blockIdx.y * 16, j0 = blockIdx.x * 16;
    int r = tid >> 4, kb = (tid & 15) * 4;
    #pragma unroll
    for (int q = 0; q < 8; ++q) {
        int k = kb + q * 64;
        float4 hv = *(const float4*)&Hh[(i0 + r) * HID + k];
        Hs[r][k] = hv.x; Hs[r][k + 1] = hv.y; Hs[r][k + 2] = hv.z; Hs[r][k + 3] = hv.w;
        float4 mv = *(const float4*)&Mh[(j0 + r) * HID + k];
        Ms[r][k] = mv.x; Ms[r][k + 1] = mv.y; Ms[r][k + 2] = mv.z; Ms[r][k + 3] = mv.w;
    }
    wW[tid] = outW[tid];
    wW[tid + 256] = outW[tid + 256];
    __syncthreads();
    int ti = tid >> 4, tj = tid & 15;
    float acc = 0.f;
    #pragma unroll 4
    for (int k = 0; k < 512; ++k)
        acc += ftanh(Hs[ti][k] + Ms[tj][k]) * wW[k];
    out[(i0 + ti) * NSEQ + (j0 + tj)] = acc + outB[0];
}

// ---------------- relation scorer ----------------
__global__ __launch_bounds__(256) void rel_kernel(
        const float* __restrict__ Rh, const float* __restrict__ Rm,
        const float* __restrict__ routW, const float* __restrict__ routB,
        float* __restrict__ out) {
    alignas(16) __shared__ float act_t[64][68];
    alignas(16) __shared__ float rw[64 * 100];
    __shared__ float rh_s[64];
    int tid = threadIdx.x;
    int i = blockIdx.x >> 3;
    int j0 = (blockIdx.x & 7) * 64;
    int rt = tid % 25, pg = tid / 25;   // valid when tid<200
    bool active = tid < 200;
    float acc[8][4] = {};
    int p = tid & 63, ksl = tid >> 6;
    for (int c = 0; c < 8; ++c) {
        int k0 = c * 64;
        #pragma unroll
        for (int q = 0; q < 25; ++q)
            rw[q * 256 + tid] = routW[k0 * 100 + q * 256 + tid];
        if (tid < 64) rh_s[tid] = Rh[i * HID + k0 + tid];
        __syncthreads();
        #pragma unroll
        for (int kk4 = 0; kk4 < 4; ++kk4) {
            int k = ksl * 16 + kk4 * 4;
            float4 mv = *(const float4*)&Rm[(j0 + p) * HID + k0 + k];
            act_t[k + 0][p] = ftanh(rh_s[k + 0] + mv.x);
            act_t[k + 1][p] = ftanh(rh_s[k + 1] + mv.y);
            act_t[k + 2][p] = ftanh(rh_s[k + 2] + mv.z);
            act_t[k + 3][p] = ftanh(rh_s[k + 3] + mv.w);
        }
        __syncthreads();
        if (active) {
            #pragma unroll 4
            for (int k = 0; k < 64; ++k) {
                float4 a0 = *(const float4*)&act_t[k][pg * 8];
                float4 a1 = *(const float4*)&act_t[k][pg * 8 + 4];
                float4 wv = *(const float4*)&rw[k * 100 + rt * 4];
                float av[8] = {a0.x, a0.y, a0.z, a0.w, a1.x, a1.y, a1.z, a1.w};
                float wf[4] = {wv.x, wv.y, wv.z, wv.w};
                #pragma unroll
                for (int pp = 0; pp < 8; ++pp)
                    #pragma unroll
                    for (int rr = 0; rr < 4; ++rr)
                        acc[pp][rr] = fmaf(av[pp], wf[rr], acc[pp][rr]);
            }
        }
        __syncthreads();
    }
    if (active) {
        #pragma unroll
        for (int pp = 0; pp < 8; ++pp) {
            int j = j0 + pg * 8 + pp;
            #pragma unroll
            for (int rr = 0; rr < 4; ++rr) {
                int rg = rt * 4 + rr;
                out[(long long)(i * NSEQ + j) * NREL + rg] = acc[pp][rr] + routB[rg];
            }
        }
    }
}

extern "C" void kernel_launch(void* const* d_in, const int* in_sizes, int n_in,
                              void* d_out, int out_size, void* d_ws, size_t ws_size,
                              hipStream_t stream) {
    const int*   tokens = (const int*)d_in[0];
    const float* E      = (const float*)d_in[1];
    const float* Wx_f1  = (const float*)d_in[2];
    const float* Wh_f1  = (const float*)d_in[3];
    const float* b_f1   = (const float*)d_in[4];
    const float* Wx_b1  = (const float*)d_in[5];
    const float* Wh_b1  = (const float*)d_in[6];
    const float* b_b1   = (const float*)d_in[7];
    const float* Wx_f2  = (const float*)d_in[8];
    const float* Wh_f2  = (const float*)d_in[9];
    const float* b_f2   = (const float*)d_in[10];
    const float* Wx_b2  = (const float*)d_in[11];
    const float* Wh_b2  = (const float*)d_in[12];
    const float* b_b2   = (const float*)d_in[13];
    const float* hidFOH = (const float*)d_in[14];
    const float* hidFOM = (const float*)d_in[15];
    const float* hidBias= (const float*)d_in[16];
    const float* outW   = (const float*)d_in[17];
    const float* outB   = (const float*)d_in[18];
    const float* rhidFOH= (const float*)d_in[19];
    const float* rhidFOM= (const float*)d_in[20];
    const float* rhidBias=(const float*)d_in[21];
    const float* routW  = (const float*)d_in[22];
    const float* routB  = (const float*)d_in[23];

    float* ws  = (float*)d_ws;
    float* x   = ws;                  // 512*256
    float* Xf1 = x + 131072;          // 512*1024
    float* Xb1 = Xf1 + 524288;
    float* h1  = Xb1 + 524288;        // 512*512
    float* Xf2 = h1 + 262144;
    float* Xb2 = Xf2 + 524288;
    float* h2  = Xb2 + 524288;        // 512*512
    float* Hh  = h2 + 262144;
    float* Mh  = Hh + 262144;
    float* Rh  = Mh + 262144;
    float* Rm  = Rh + 262144;
    // stage: 2 layers x (2 dirs x 2 slots x 256) u64, 8-byte aligned
    unsigned long long* stage1 = (unsigned long long*)(Rm + 262144);
    unsigned long long* stage2 = stage1 + 1024;

    float* arc_out = (float*)d_out;
    float* rel_out = arc_out + NSEQ * NSEQ;

    hipMemsetAsync(stage1, 0, 2048 * sizeof(unsigned long long), stream);
    embed_kernel<<<NSEQ, WD, 0, stream>>>(tokens, E, x);
    dim3 g1(NG / 64, NSEQ / 64);
    gemm_bias_kernel<<<g1, 256, 0, stream>>>(x, Wx_f1, b_f1, Xf1, NSEQ, WD, NG);
    gemm_bias_kernel<<<g1, 256, 0, stream>>>(x, Wx_b1, b_b1, Xb1, NSEQ, WD, NG);
    lstm_kernel<<<8, 1024, 0, stream>>>(Xf1, Xb1, Wh_f1, Wh_b1, h1, stage1);
    gemm_bias_kernel<<<g1, 256, 0, stream>>>(h1, Wx_f2, b_f2, Xf2, NSEQ, FEAT, NG);
    gemm_bias_kernel<<<g1, 256, 0, stream>>>(h1, Wx_b2, b_b2, Xb2, NSEQ, FEAT, NG);
    lstm_kernel<<<8, 1024, 0, stream>>>(Xf2, Xb2, Wh_f2, Wh_b2, h2, stage2);
    dim3 g2(HID / 64, NSEQ / 64);
    gemm_bias_kernel<<<g2, 256, 0, stream>>>(h2, hidFOH, hidBias, Hh, NSEQ, FEAT, HID);
    gemm_bias_kernel<<<g2, 256, 0, stream>>>(h2, hidFOM, nullptr, Mh, NSEQ, FEAT, HID);
    gemm_bias_kernel<<<g2, 256, 0, stream>>>(h2, rhidFOH, rhidBias, Rh, NSEQ, FEAT, HID);
    gemm_bias_kernel<<<g2, 256, 0, stream>>>(h2, rhidFOM, nullptr, Rm, NSEQ, FEAT, HID);
    dim3 ga(NSEQ / 16, NSEQ / 16);
    arc_kernel<<<ga, 256, 0, stream>>>(Hh, Mh, outW, outB, arc_out);
    rel_kernel<<<NSEQ * 8, 256, 0, stream>>>(Rh, Rm, routW, routB, rel_out);
}